// Round 21
// baseline (282.962 us; speedup 1.0000x reference)
//
#include <hip/hip_runtime.h>

#define NTOK 16384
#define DIN  512
#define DOUT 512
#define HDIM 256
#define NEXP 10
#define NSLOT (2*NTOK)
#define NSEG  (2*NEXP)

typedef unsigned short u16;
typedef unsigned int   u32;
typedef short s16x8 __attribute__((ext_vector_type(8)));
typedef float f32x4 __attribute__((ext_vector_type(4)));

__device__ __forceinline__ u16 f2b(float f){
  union { float f; u32 u; } c; c.f = f;
  u32 r = c.u + 0x7FFFu + ((c.u >> 16) & 1u);
  return (u16)(r >> 16);
}
__device__ __forceinline__ float b2f(u16 v){
  union { u32 u; float f; } c; c.u = ((u32)v) << 16; return c.f;
}
__device__ __forceinline__ u32 pk2(float lo, float hi){
  u32 r;
  asm("v_cvt_pk_bf16_f32 %0, %1, %2" : "=v"(r) : "v"(lo), "v"(hi));
  return r;
}
__device__ __forceinline__ s16x8 cvt8(const float* p){
  f32x4 a = *(const f32x4*)p;
  f32x4 b = *(const f32x4*)(p + 4);
  union { u32 u[4]; s16x8 v; } c;
  c.u[0] = pk2(a[0], a[1]); c.u[1] = pk2(a[2], a[3]);
  c.u[2] = pk2(b[0], b[1]); c.u[3] = pk2(b[2], b[3]);
  return c.v;
}

__global__ __launch_bounds__(64) void k_zero(int* counts){
  if (threadIdx.x < NSEG) counts[threadIdx.x] = 0;
}

// ---------------- gating: 16 tokens/block, x tile bulk-staged in LDS ----------------
__global__ __launch_bounds__(256) void k_gate(
    const float* __restrict__ x, const float* __restrict__ gw, const float* __restrict__ gb,
    int* __restrict__ tke, float* __restrict__ tkw, int* __restrict__ counts)
{
  __shared__ int cnt[NSEG];
  __shared__ __align__(16) float xs[16*512];
  __shared__ __align__(16) float lgw[5120];
  const int tid = threadIdx.x;
  if (tid < NSEG) cnt[tid] = 0;
  for (int d = tid; d < 512; d += 256){
    float g[10];
    #pragma unroll
    for (int r = 0; r < 10; ++r) g[r] = gw[d*10 + r];
    #pragma unroll
    for (int p = 0; p < 5; ++p){
      lgw[(p*512 + d)*2    ] = g[2*p];
      lgw[(p*512 + d)*2 + 1] = g[2*p+1];
    }
  }
  const float* xsrc = x + (size_t)blockIdx.x * 16 * 512;
  #pragma unroll
  for (int q = 0; q < 8; ++q){
    int i = tid + q*256;
    *(f32x4*)&xs[i*4] = *(const f32x4*)&xsrc[i*4];
  }
  __syncthreads();

  const int wave = tid >> 6, lane = tid & 63;
  #pragma unroll
  for (int tt = 0; tt < 4; ++tt){
    const int lt = wave*4 + tt;
    const int token = blockIdx.x*16 + lt;
    float acc[NEXP];
    #pragma unroll
    for (int e = 0; e < NEXP; ++e) acc[e] = 0.f;
    #pragma unroll
    for (int dd = 0; dd < 8; ++dd){
      int d = dd*64 + lane;
      float xv = xs[lt*512 + d];
      #pragma unroll
      for (int p = 0; p < 5; ++p){
        float2 g2 = *(const float2*)&lgw[(p*512 + d)*2];
        acc[2*p]   += xv * g2.x;
        acc[2*p+1] += xv * g2.y;
      }
    }
    #pragma unroll
    for (int e = 0; e < NEXP; ++e){
      #pragma unroll
      for (int off = 32; off > 0; off >>= 1) acc[e] += __shfl_xor(acc[e], off, 64);
    }
    if (lane == 0){
      float l[NEXP];
      #pragma unroll
      for (int e = 0; e < NEXP; ++e) l[e] = acc[e] + gb[e];
      int bi = 0; float bv = l[0];
      #pragma unroll
      for (int e = 1; e < NEXP; ++e) if (l[e] > bv){ bv = l[e]; bi = e; }
      int si = -1; float sv = -1e30f;
      #pragma unroll
      for (int e = 0; e < NEXP; ++e) if (e != bi && l[e] > sv){ sv = l[e]; si = e; }
      float w0 = 1.f / (1.f + expf(sv - bv));
      tke[2*token]   = bi;  tke[2*token+1] = si;
      tkw[2*token]   = w0;  tkw[2*token+1] = 1.f - w0;
      atomicAdd(&cnt[2*bi], 1);  atomicAdd(&cnt[2*si+1], 1);
    }
  }
  __syncthreads();
  if (tid < NSEG && cnt[tid] > 0)
    atomicAdd(&counts[tid], cnt[tid]);
}

__global__ __launch_bounds__(64) void k_scan(
    const int* __restrict__ counts, int* __restrict__ offsets, int* __restrict__ cursors)
{
  if (threadIdx.x == 0){
    int s = 0;
    for (int i = 0; i < NSEG; ++i){ offsets[i] = s; s += counts[i]; }
    offsets[NSEG] = s;
  }
  if (threadIdx.x < NSEG) cursors[threadIdx.x] = 0;
}

__global__ __launch_bounds__(256) void k_scatter(
    const int* __restrict__ tke, const float* __restrict__ tkw,
    const int* __restrict__ offsets, int* __restrict__ cursors,
    int* __restrict__ tok_slot, float* __restrict__ w_slot)
{
  __shared__ int lcnt[NSEG], lbase[NSEG];
  if (threadIdx.x < NSEG) lcnt[threadIdx.x] = 0;
  __syncthreads();
  int n = blockIdx.x * 256 + threadIdx.x;
  int g0 = 2*tke[2*n], g1 = 2*tke[2*n+1] + 1;
  int p0 = atomicAdd(&lcnt[g0], 1);
  int p1 = atomicAdd(&lcnt[g1], 1);
  __syncthreads();
  if (threadIdx.x < NSEG) lbase[threadIdx.x] = atomicAdd(&cursors[threadIdx.x], lcnt[threadIdx.x]);
  __syncthreads();
  int s0 = offsets[g0] + lbase[g0] + p0;
  int s1 = offsets[g1] + lbase[g1] + p1;
  tok_slot[s0] = n; w_slot[s0] = tkw[2*n];
  tok_slot[s1] = n; w_slot[s1] = tkw[2*n+1];
}

// ---------------- prep: W[e][K][C] f32 -> fragment-tiled bf16 ----------------
// dst[((e*C16+cg)*KC8 + kc)*128 + c16*8 + q] = bf16(W[e][kc*8+q][cg*16+c16])
__global__ __launch_bounds__(256) void k_wtf(
    const float* __restrict__ W, u16* __restrict__ out, int KC8, int C16)
{
  const int e   = blockIdx.z;
  const int gid = blockIdx.x * 256 + threadIdx.x;
  const int c16 = gid & 15;
  const int rem = gid >> 4;
  const int kc  = rem % KC8;
  const int cg  = rem / KC8;
  const int K = KC8 * 8, C = C16 * 16;
  const float* src = W + (size_t)e*K*C + (size_t)(kc*8)*C + cg*16 + c16;
  s16x8 v;
  #pragma unroll
  for (int q = 0; q < 8; ++q)
    v[q] = (short)f2b(src[(size_t)q * C]);
  size_t t = ((size_t)e*C16 + cg)*KC8 + kc;
  *(s16x8*)(out + t*128 + c16*8) = v;
}

// ---------------- k_ey: fused expert MLP for one (expert, rank) segment ----------------
// 64 slots/block; h[64][256] lives in LDS (stride 264); cmb (+)= wts*(relu(xW1+b1)W2+b2)
template<int PASS>
__global__ __launch_bounds__(512, 4) void k_ey(
    const float* __restrict__ x,
    const u16* __restrict__ w1f, const float* __restrict__ b1,
    const u16* __restrict__ w2f, const float* __restrict__ b2,
    const int* __restrict__ offsets, const int* __restrict__ tok_slot,
    const float* __restrict__ w_slot, u16* __restrict__ cmb)
{
  __shared__ __align__(16) char pool[50176];   // As dbuf 2x8K | hbuf 64x264 u16; stage reuses pool
  u16* As   = (u16*)pool;
  u16* hbuf = (u16*)(pool + 16384);            // stride 264 (256 cols + 8 pad)
  __shared__ int   toks[64];
  __shared__ float wts[64];
  const int e    = blockIdx.z;
  const int segb = offsets[2*e + PASS];
  const int segc = offsets[2*e + PASS + 1] - segb;
  const int c0   = blockIdx.x * 64;
  if (c0 >= segc) return;
  const int tid  = threadIdx.x;

  if (tid < 64){
    int r = c0 + tid;
    int s = segb + (r < segc ? r : segc - 1);
    toks[tid] = tok_slot[s];
    wts[tid]  = w_slot[s];
  }
  __syncthreads();

  const int crow = tid >> 3;           // 0..63
  const int ckk  = (tid & 7) * 8;      // k within 64
  const int tokr = toks[crow];

  s16x8 ra;
  auto loadregs = [&](int ks){
    ra = cvt8(x + (size_t)tokr*DIN + ks*64 + ckk);
  };
  auto writeregs = [&](int buf){
    u32 byt = (u32)((crow*64 + ckk)*2) ^ ((u32)(crow&7)<<4);
    *(s16x8*)((char*)As + buf*8192 + byt) = ra;
  };

  const int wv = tid >> 6, lane = tid & 63;
  const int lr = lane & 15, lk = lane >> 4;
  const int wr = (wv >> 1) * 16;       // row group (4 groups x 16)
  const int ch = wv & 1;               // col half

  // -------- phase 1: h = relu(x W1e + b1e) --------
  f32x4 acc1[8];
  #pragma unroll
  for (int j = 0; j < 8; ++j) acc1[j] = (f32x4){0.f,0.f,0.f,0.f};
  const int cgb1 = e*16 + ch*8;        // w1f col-group base (KC8=64)

  loadregs(0); writeregs(0);
  int cur = 0;
  for (int ks = 0; ks < 8; ++ks){
    __syncthreads();
    if (ks + 1 < 8) loadregs(ks + 1);
    #pragma unroll
    for (int sub = 0; sub < 2; ++sub){
      int kc = ks*8 + sub*4 + lk;
      int arow = wr + lr;
      u32 ab = (u32)((arow*64 + sub*32 + lk*8)*2) ^ ((u32)(arow&7)<<4);
      s16x8 af = *(const s16x8*)((char*)As + cur*8192 + ab);
      #pragma unroll
      for (int g = 0; g < 8; ++g){
        s16x8 bf = *(const s16x8*)(w1f + ((size_t)(cgb1 + g)*64 + kc)*128 + lr*8);
        acc1[g] = __builtin_amdgcn_mfma_f32_16x16x32_bf16(af, bf, acc1[g], 0, 0, 0);
      }
    }
    if (ks + 1 < 8) writeregs(cur ^ 1);
    cur ^= 1;
  }
  // write h tile (bf16) into hbuf
  #pragma unroll
  for (int g = 0; g < 8; ++g){
    int col = ch*128 + g*16 + lr;
    float bias = b1[e*HDIM + col];
    #pragma unroll
    for (int r = 0; r < 4; ++r){
      int row = wr + lk*4 + r;
      float v = acc1[g][r] + bias;
      hbuf[row*264 + col] = f2b(v > 0.f ? v : 0.f);
    }
  }
  __syncthreads();   // hbuf ready; As dead

  // -------- phase 2: y = h W2e + b2e (wave: 16 rows x 256 cols) --------
  f32x4 acc2[16];
  #pragma unroll
  for (int g = 0; g < 16; ++g) acc2[g] = (f32x4){0.f,0.f,0.f,0.f};
  const int cgb2 = e*32 + ch*16;       // w2f col-group base (KC8=32)

  for (int kk = 0; kk < 8; ++kk){      // K = 256, 32 per step
    s16x8 af = *(const s16x8*)&hbuf[(wr + lr)*264 + kk*32 + lk*8];
    int kc = kk*4 + lk;
    #pragma unroll
    for (int g = 0; g < 16; ++g){
      s16x8 bf = *(const s16x8*)(w2f + ((size_t)(cgb2 + g)*32 + kc)*128 + lr*8);
      acc2[g] = __builtin_amdgcn_mfma_f32_16x16x32_bf16(af, bf, acc2[g], 0, 0, 0);
    }
  }
  __syncthreads();   // all hbuf reads done; pool reusable as stage

  // -------- epilogue: two 256-col chunks via LDS stage, contiguous cmb writes --------
  u16* stage = (u16*)pool;             // [64][264] u16
  #pragma unroll
  for (int cc = 0; cc < 2; ++cc){
    if (ch == cc){
      #pragma unroll
      for (int g = 0; g < 16; ++g){
        int col = g*16 + lr;
        float bias = b2[e*DOUT + cc*256 + col];
        #pragma unroll
        for (int r = 0; r < 4; ++r){
          int row = wr + lk*4 + r;
          stage[row*264 + col] = f2b(wts[row] * (acc2[g][r] + bias));
        }
      }
    }
    __syncthreads();
    {
      int row = tid >> 3, t8 = tid & 7;
      if (c0 + row < segc){
        u16* dst = cmb + (size_t)toks[row] * 1024 + cc*256 + t8*32;
        const u16* src = stage + row*264 + t8*32;
        #pragma unroll
        for (int q = 0; q < 4; ++q){
          s16x8 s = *(const s16x8*)(src + q*8);
          if (PASS == 1){
            s16x8 old = *(const s16x8*)(dst + q*8);
            #pragma unroll
            for (int m = 0; m < 8; ++m)
              s[m] = (short)f2b(b2f((u16)old[m]) + b2f((u16)s[m]));
          }
          *(s16x8*)(dst + q*8) = s;
        }
      }
    }
    __syncthreads();
  }
}

// ---------------- k_cls: DISJOINT: reads strided cmb [32,64M), writes cls [0,32M) ----------
__global__ __launch_bounds__(512, 4) void k_cls(
    const u16* __restrict__ cmb, const float* __restrict__ W,
    const float* __restrict__ bias, float* __restrict__ out)
{
  __shared__ __align__(16) char Bs[2][10240];   // 128 cols x 80B
  const int tid = threadIdx.x;
  const int r0  = blockIdx.x * 256;
  const int c0  = blockIdx.y * 128;

  const int bc4 = tid >> 4;
  const int bkp = tid & 15;
  u32 bpk[4];
  auto loadB = [&](int ks){
    const float* p0 = W + (size_t)(ks*32 + 2*bkp) * DOUT + c0 + bc4*4;
    f32x4 v0 = *(const f32x4*)p0;
    f32x4 v1 = *(const f32x4*)(p0 + DOUT);
    #pragma unroll
    for (int m = 0; m < 4; ++m) bpk[m] = pk2(v0[m], v1[m]);
  };
  auto writeB = [&](int buf){
    #pragma unroll
    for (int m = 0; m < 4; ++m)
      *(u32*)(Bs[buf] + (bc4*4 + m)*80 + bkp*4) = bpk[m];
  };

  const int wv = tid >> 6, lane = tid & 63;
  const int lr = lane & 15, lk = lane >> 4;
  const int rg = wv >> 1, cg = wv & 1;
  const u16* Arow = cmb + (size_t)(r0 + rg*64) * 1024;

  f32x4 acc[4][4];
  #pragma unroll
  for (int i = 0; i < 4; ++i)
    #pragma unroll
    for (int j = 0; j < 4; ++j) acc[i][j] = (f32x4){0.f,0.f,0.f,0.f};

  s16x8 af[4], afn[4];
  auto loadA = [&](s16x8* a, int ks){
    #pragma unroll
    for (int g = 0; g < 4; ++g)
      a[g] = *(const s16x8*)(Arow + (size_t)(g*16 + lr)*1024 + ks*32 + lk*8);
  };

  loadB(0); writeB(0); loadA(af, 0);
  int cur = 0;
  for (int ks = 0; ks < 16; ++ks){
    __syncthreads();
    if (ks + 1 < 16){ loadB(ks + 1); loadA(afn, ks + 1); }
    s16x8 bf[4];
    #pragma unroll
    for (int j = 0; j < 4; ++j)
      bf[j] = *(const s16x8*)(Bs[cur] + (cg*64 + j*16 + lr)*80 + lk*16);
    #pragma unroll
    for (int i = 0; i < 4; ++i)
      #pragma unroll
      for (int j = 0; j < 4; ++j)
        acc[i][j] = __builtin_amdgcn_mfma_f32_16x16x32_bf16(af[i], bf[j], acc[i][j], 0, 0, 0);
    if (ks + 1 < 16) writeB(cur ^ 1);
    #pragma unroll
    for (int g = 0; g < 4; ++g) af[g] = afn[g];
    cur ^= 1;
  }

  #pragma unroll
  for (int j = 0; j < 4; ++j){
    int col = c0 + cg*64 + j*16 + lr;
    float bv = bias[col];
    #pragma unroll
    for (int i = 0; i < 4; ++i)
      #pragma unroll
      for (int r = 0; r < 4; ++r){
        int row = r0 + rg*64 + i*16 + lk*4 + r;
        out[(size_t)row * DOUT + col] = acc[i][j][r] + bv;
      }
  }
}

// ---------------- k_vip (fallback): vec in place, 64-row blocks ----------------
__global__ __launch_bounds__(512, 2) void k_vip(
    const float* __restrict__ W, const float* __restrict__ bias,
    u16* __restrict__ cmbio)
{
  __shared__ __align__(16) char Bs[2][40960];
  const int tid = threadIdx.x;
  const int r0  = blockIdx.x * 64;

  int bc4[4], bkp[4];
  #pragma unroll
  for (int u = 0; u < 4; ++u){
    int idx = tid + u*512;
    bc4[u] = idx >> 4;
    bkp[u] = idx & 15;
  }
  u32 bpk[4][4];
  auto loadB = [&](int ks){
    #pragma unroll
    for (int u = 0; u < 4; ++u){
      const float* p0 = W + (size_t)(ks*32 + 2*bkp[u]) * DOUT + bc4[u]*4;
      f32x4 v0 = *(const f32x4*)p0;
      f32x4 v1 = *(const f32x4*)(p0 + DOUT);
      #pragma unroll
      for (int m = 0; m < 4; ++m) bpk[u][m] = pk2(v0[m], v1[m]);
    }
  };
  auto writeB = [&](int buf){
    #pragma unroll
    for (int u = 0; u < 4; ++u)
      #pragma unroll
      for (int m = 0; m < 4; ++m)
        *(u32*)(Bs[buf] + (bc4[u]*4 + m)*80 + bkp[u]*4) = bpk[u][m];
  };

  const int wv = tid >> 6, lane = tid & 63;
  const int lr = lane & 15, lk = lane >> 4;
  const int wc = wv * 64;
  const u16* Arow = cmbio + (size_t)r0 * 1024;

  f32x4 acc[4][4];
  #pragma unroll
  for (int i = 0; i < 4; ++i)
    #pragma unroll
    for (int j = 0; j < 4; ++j) acc[i][j] = (f32x4){0.f,0.f,0.f,0.f};

  s16x8 af[4], afn[4];
  auto loadA = [&](s16x8* a, int ks){
    #pragma unroll
    for (int g = 0; g < 4; ++g)
      a[g] = *(const s16x8*)(Arow + (size_t)(g*16 + lr)*1024 + ks*32 + lk*8);
  };

  loadB(0); writeB(0); loadA(af, 0);
  int cur = 0;
  for (int ks = 0; ks < 16; ++ks){
    __syncthreads();
    if (ks + 1 < 16){ loadB(ks + 1); loadA(afn, ks + 1); }
    s16x8 bf[4];
    #pragma unroll
    for (int g = 0; g < 4; ++g)
      bf[g] = *(const s16x8*)(Bs[cur] + (wc + g*16 + lr)*80 + lk*16);
    #pragma unroll
    for (int i = 0; i < 4; ++i)
      #pragma unroll
      for (int j = 0; j < 4; ++j)
        acc[i][j] = __builtin_amdgcn_mfma_f32_16x16x32_bf16(af[i], bf[j], acc[i][j], 0, 0, 0);
    if (ks + 1 < 16) writeB(cur ^ 1);
    #pragma unroll
    for (int g = 0; g < 4; ++g) af[g] = afn[g];
    cur ^= 1;
  }
  __syncthreads();

  float* out = (float*)cmbio;
  #pragma unroll
  for (int j = 0; j < 4; ++j){
    int col = wc + j*16 + lr;
    float bv = bias[col];
    #pragma unroll
    for (int i = 0; i < 4; ++i)
      #pragma unroll
      for (int r = 0; r < 4; ++r){
        int row = r0 + i*16 + lk*4 + r;
        out[(size_t)row * DOUT + col] = acc[i][j][r] + bv;
      }
  }
}

// ---------------- k_vipw (ws path): vec in place, tiled-B from d_ws, 2-deep pipe ----------
__global__ __launch_bounds__(256, 2) void k_vipw(
    const u16* __restrict__ wTt, const float* __restrict__ bias,
    u16* __restrict__ cmbio)
{
  const int tid = threadIdx.x;
  const int r0  = blockIdx.x * 32;
  const int wv = tid >> 6, lane = tid & 63;
  const int lr = lane & 15, lk = lane >> 4;
  const int wc = wv * 128;
  const int cg0 = wv * 8;
  const u16* Arow = cmbio + (size_t)r0 * 1024;

  f32x4 acc[2][8];
  #pragma unroll
  for (int i = 0; i < 2; ++i)
    #pragma unroll
    for (int j = 0; j < 8; ++j) acc[i][j] = (f32x4){0.f,0.f,0.f,0.f};

  s16x8 a0[2], b0[8], a1[2], b1[8];
  auto loadA = [&](s16x8* a, int ks){
    #pragma unroll
    for (int g = 0; g < 2; ++g)
      a[g] = *(const s16x8*)(Arow + (size_t)(g*16 + lr)*1024 + ks*32 + lk*8);
  };
  auto loadB = [&](s16x8* b, int ks){
    #pragma unroll
    for (int j = 0; j < 8; ++j){
      int chunk = (cg0 + j)*64 + ks*4 + lk;
      b[j] = *(const s16x8*)(wTt + (size_t)chunk*128 + lr*8);
    }
  };
  auto step = [&](const s16x8* a, const s16x8* b){
    #pragma unroll
    for (int j = 0; j < 8; ++j)
      #pragma unroll
      for (int i = 0; i < 2; ++i)
        acc[i][j] = __builtin_amdgcn_mfma_f32_16x16x32_bf16(a[i], b[j], acc[i][j], 0, 0, 0);
  };

  loadA(a0, 0); loadB(b0, 0);
  #pragma unroll
  for (int ks = 0; ks < 16; ks += 2){
    if (ks + 1 < 16){ loadA(a1, ks + 1); loadB(b1, ks + 1); }
    step(a0, b0);
    if (ks + 2 < 16){ loadA(a0, ks + 2); loadB(b0, ks + 2); }
    step(a1, b1);
  }
  __syncthreads();

  float* out = (float*)cmbio;
  #pragma unroll
  for (int j = 0; j < 8; ++j){
    int col = wc + j*16 + lr;
    float bv = bias[col];
    #pragma unroll
    for (int i = 0; i < 2; ++i)
      #pragma unroll
      for (int r = 0; r < 4; ++r){
        int row = r0 + i*16 + lk*4 + r;
        out[(size_t)row * DOUT + col] = acc[i][j][r] + bv;
      }
  }
}

extern "C" void kernel_launch(void* const* d_in, const int* in_sizes, int n_in,
                              void* d_out, int out_size, void* d_ws, size_t ws_size,
                              hipStream_t stream)
{
  const float* x    = (const float*)d_in[0];
  const float* gw   = (const float*)d_in[1];
  const float* gb   = (const float*)d_in[2];
  const float* w1   = (const float*)d_in[3];
  const float* b1   = (const float*)d_in[4];
  const float* w2   = (const float*)d_in[5];
  const float* b2   = (const float*)d_in[6];
  const float* clsw = (const float*)d_in[7];
  const float* clsb = (const float*)d_in[8];
  const float* vecw = (const float*)d_in[9];
  const float* vecb = (const float*)d_in[10];

  char* base = (char*)d_out;
  float* cls_out  = (float*)base;                               // [0,32Mi)
  u16*   cmb      = (u16*)(base + ((size_t)32<<20));            // strided in vec half
  char*  mb       = base + ((size_t)16<<20) + (128<<10);
  int*   tok_slot = (int*)  mb;
  float* w_slot   = (float*)(mb + 131072);
  int*   tke      = (int*)  (mb + 262144);
  float* tkw      = (float*)(mb + 393216);
  int*   counts   = (int*)  (mb + 524288);
  int*   offsets  = (int*)  (mb + 524544);
  int*   cursors  = (int*)  (mb + 524800);
  u16*   w1f      = (u16*)(base + ((size_t)18<<20));            // tiled bf16, 2.62MB
  u16*   w2f      = (u16*)(base + ((size_t)21<<20));            // tiled bf16, 2.62MB

  const bool usews = (ws_size >= (size_t)(1<<20));
  u16* vecwTt = (u16*)d_ws;            // fragment-tiled vec weight, 512KB

  k_zero<<<dim3(1), dim3(64), 0, stream>>>(counts);
  k_gate<<<dim3(NTOK/16), dim3(256), 0, stream>>>(x, gw, gb, tke, tkw, counts);
  k_scan<<<dim3(1), dim3(64), 0, stream>>>(counts, offsets, cursors);
  k_scatter<<<dim3(NTOK/256), dim3(256), 0, stream>>>(tke, tkw, offsets, cursors,
                                                      tok_slot, w_slot);
  k_wtf<<<dim3(64, 1, NEXP), dim3(256), 0, stream>>>(w1, w1f, 64, 16);
  k_wtf<<<dim3(64, 1, NEXP), dim3(256), 0, stream>>>(w2, w2f, 32, 32);
  if (usews)
    k_wtf<<<dim3(128, 1, 1), dim3(256), 0, stream>>>(vecw, vecwTt, 64, 32);
  // fused expert MLP (h stays in LDS); rank-0 pass then rank-1 RMW pass
  k_ey<0><<<dim3(256, 1, NEXP), dim3(512), 0, stream>>>(x, w1f, b1, w2f, b2,
                                                        offsets, tok_slot, w_slot, cmb);
  k_ey<1><<<dim3(256, 1, NEXP), dim3(512), 0, stream>>>(x, w1f, b1, w2f, b2,
                                                        offsets, tok_slot, w_slot, cmb);
  k_cls<<<dim3(NTOK/256, DOUT/128), dim3(512), 0, stream>>>(cmb, clsw, clsb, cls_out);
  if (usews)
    k_vipw<<<dim3(NTOK/32), dim3(256), 0, stream>>>(vecwTt, vecb, cmb);
  else
    k_vip<<<dim3(NTOK/64), dim3(512), 0, stream>>>(vecw, vecb, cmb);
}

// Round 22
// 202.723 us; speedup vs baseline: 1.3958x; 1.3958x over previous
//
#include <hip/hip_runtime.h>

#define NTOK 16384
#define DIN  512
#define DOUT 512
#define HDIM 256
#define NEXP 10
#define NSLOT (2*NTOK)
#define NSEG  (2*NEXP)
#define BM 128
#define BN 128
#define BK 64

typedef unsigned short u16;
typedef unsigned int   u32;
typedef short s16x8 __attribute__((ext_vector_type(8)));
typedef float f32x4 __attribute__((ext_vector_type(4)));

__device__ __forceinline__ u16 f2b(float f){
  union { float f; u32 u; } c; c.f = f;
  u32 r = c.u + 0x7FFFu + ((c.u >> 16) & 1u);
  return (u16)(r >> 16);
}
__device__ __forceinline__ float b2f(u16 v){
  union { u32 u; float f; } c; c.u = ((u32)v) << 16; return c.f;
}
__device__ __forceinline__ u32 pk2(float lo, float hi){
  u32 r;
  asm("v_cvt_pk_bf16_f32 %0, %1, %2" : "=v"(r) : "v"(lo), "v"(hi));
  return r;
}
__device__ __forceinline__ s16x8 cvt8(const float* p){
  f32x4 a = *(const f32x4*)p;
  f32x4 b = *(const f32x4*)(p + 4);
  union { u32 u[4]; s16x8 v; } c;
  c.u[0] = pk2(a[0], a[1]); c.u[1] = pk2(a[2], a[3]);
  c.u[2] = pk2(b[0], b[1]); c.u[3] = pk2(b[2], b[3]);
  return c.v;
}

__global__ __launch_bounds__(64) void k_zero(int* counts){
  if (threadIdx.x < NSEG) counts[threadIdx.x] = 0;
}

// ---------------- gating: 16 tokens/block, x tile bulk-staged in LDS ----------------
__global__ __launch_bounds__(256) void k_gate(
    const float* __restrict__ x, const float* __restrict__ gw, const float* __restrict__ gb,
    int* __restrict__ tke, float* __restrict__ tkw, int* __restrict__ counts)
{
  __shared__ int cnt[NSEG];
  __shared__ __align__(16) float xs[16*512];
  __shared__ __align__(16) float lgw[5120];
  const int tid = threadIdx.x;
  if (tid < NSEG) cnt[tid] = 0;
  for (int d = tid; d < 512; d += 256){
    float g[10];
    #pragma unroll
    for (int r = 0; r < 10; ++r) g[r] = gw[d*10 + r];
    #pragma unroll
    for (int p = 0; p < 5; ++p){
      lgw[(p*512 + d)*2    ] = g[2*p];
      lgw[(p*512 + d)*2 + 1] = g[2*p+1];
    }
  }
  const float* xsrc = x + (size_t)blockIdx.x * 16 * 512;
  #pragma unroll
  for (int q = 0; q < 8; ++q){
    int i = tid + q*256;
    *(f32x4*)&xs[i*4] = *(const f32x4*)&xsrc[i*4];
  }
  __syncthreads();

  const int wave = tid >> 6, lane = tid & 63;
  #pragma unroll
  for (int tt = 0; tt < 4; ++tt){
    const int lt = wave*4 + tt;
    const int token = blockIdx.x*16 + lt;
    float acc[NEXP];
    #pragma unroll
    for (int e = 0; e < NEXP; ++e) acc[e] = 0.f;
    #pragma unroll
    for (int dd = 0; dd < 8; ++dd){
      int d = dd*64 + lane;
      float xv = xs[lt*512 + d];
      #pragma unroll
      for (int p = 0; p < 5; ++p){
        float2 g2 = *(const float2*)&lgw[(p*512 + d)*2];
        acc[2*p]   += xv * g2.x;
        acc[2*p+1] += xv * g2.y;
      }
    }
    #pragma unroll
    for (int e = 0; e < NEXP; ++e){
      #pragma unroll
      for (int off = 32; off > 0; off >>= 1) acc[e] += __shfl_xor(acc[e], off, 64);
    }
    if (lane == 0){
      float l[NEXP];
      #pragma unroll
      for (int e = 0; e < NEXP; ++e) l[e] = acc[e] + gb[e];
      int bi = 0; float bv = l[0];
      #pragma unroll
      for (int e = 1; e < NEXP; ++e) if (l[e] > bv){ bv = l[e]; bi = e; }
      int si = -1; float sv = -1e30f;
      #pragma unroll
      for (int e = 0; e < NEXP; ++e) if (e != bi && l[e] > sv){ sv = l[e]; si = e; }
      float w0 = 1.f / (1.f + expf(sv - bv));
      tke[2*token]   = bi;  tke[2*token+1] = si;
      tkw[2*token]   = w0;  tkw[2*token+1] = 1.f - w0;
      atomicAdd(&cnt[2*bi], 1);  atomicAdd(&cnt[2*si+1], 1);
    }
  }
  __syncthreads();
  if (tid < NSEG && cnt[tid] > 0)
    atomicAdd(&counts[tid], cnt[tid]);
}

__global__ __launch_bounds__(64) void k_scan(
    const int* __restrict__ counts, int* __restrict__ offsets, int* __restrict__ cursors)
{
  if (threadIdx.x == 0){
    int s = 0;
    for (int i = 0; i < NSEG; ++i){ offsets[i] = s; s += counts[i]; }
    offsets[NSEG] = s;
  }
  if (threadIdx.x < NSEG) cursors[threadIdx.x] = 0;
}

__global__ __launch_bounds__(256) void k_scatter(
    const int* __restrict__ tke, const float* __restrict__ tkw,
    const int* __restrict__ offsets, int* __restrict__ cursors,
    int* __restrict__ tok_slot, float* __restrict__ w_slot)
{
  __shared__ int lcnt[NSEG], lbase[NSEG];
  if (threadIdx.x < NSEG) lcnt[threadIdx.x] = 0;
  __syncthreads();
  int n = blockIdx.x * 256 + threadIdx.x;
  int g0 = 2*tke[2*n], g1 = 2*tke[2*n+1] + 1;
  int p0 = atomicAdd(&lcnt[g0], 1);
  int p1 = atomicAdd(&lcnt[g1], 1);
  __syncthreads();
  if (threadIdx.x < NSEG) lbase[threadIdx.x] = atomicAdd(&cursors[threadIdx.x], lcnt[threadIdx.x]);
  __syncthreads();
  int s0 = offsets[g0] + lbase[g0] + p0;
  int s1 = offsets[g1] + lbase[g1] + p1;
  tok_slot[s0] = n; w_slot[s0] = tkw[2*n];
  tok_slot[s1] = n; w_slot[s1] = tkw[2*n+1];
}

// ---------------- prep: W[e][K][C] f32 -> fragment-tiled bf16 ----------------
// dst[((e*C16+cg)*KC8 + kc)*128 + c16*8 + q] = bf16(W[e][kc*8+q][cg*16+c16])
__global__ __launch_bounds__(256) void k_wtf(
    const float* __restrict__ W, u16* __restrict__ out, int KC8, int C16)
{
  const int e   = blockIdx.z;
  const int gid = blockIdx.x * 256 + threadIdx.x;
  const int c16 = gid & 15;
  const int rem = gid >> 4;
  const int kc  = rem % KC8;
  const int cg  = rem / KC8;
  const int K = KC8 * 8, C = C16 * 16;
  const float* src = W + (size_t)e*K*C + (size_t)(kc*8)*C + cg*16 + c16;
  s16x8 v;
  #pragma unroll
  for (int q = 0; q < 8; ++q)
    v[q] = (short)f2b(src[(size_t)q * C]);
  size_t t = ((size_t)e*C16 + cg)*KC8 + kc;
  *(s16x8*)(out + t*128 + c16*8) = v;
}

// ---------------- k_h: h = relu(x[tok] W1e + b1e); A via LDS, B tiled-direct ----------------
__global__ __launch_bounds__(256, 3) void k_h(
    const float* __restrict__ x, const u16* __restrict__ w1f, const float* __restrict__ b1,
    const int* __restrict__ offsets, const int* __restrict__ tok_slot,
    u16* __restrict__ h)
{
  __shared__ __align__(16) char pool[34816];   // As dbuf 2x16K; reused as outh [128][136]
  u16* As = (u16*)pool;
  __shared__ int toks[BM];
  const int e   = blockIdx.z;
  const int hh  = blockIdx.y;                  // HDIM half
  const int off = offsets[2*e];
  const int cnt = offsets[2*e+2] - off;
  const int c0  = blockIdx.x * BM;
  if (c0 >= cnt) return;
  const int tid = threadIdx.x;

  if (tid < BM){
    int r = c0 + tid;
    toks[tid] = tok_slot[off + (r < cnt ? r : cnt - 1)];
  }
  __syncthreads();

  int crow[4], ckk[4];
  #pragma unroll
  for (int i = 0; i < 4; ++i){
    int c = tid + i*256;
    crow[i] = c >> 3; ckk[i] = (c & 7) * 8;
  }
  int tokr[4];
  #pragma unroll
  for (int i = 0; i < 4; ++i) tokr[i] = toks[crow[i]];

  s16x8 ra[4];
  auto loadregs = [&](int ks){
    #pragma unroll
    for (int i = 0; i < 4; ++i)
      ra[i] = cvt8(x + (size_t)tokr[i]*DIN + ks*BK + ckk[i]);
  };
  auto writeregs = [&](int buf){
    #pragma unroll
    for (int i = 0; i < 4; ++i){
      u32 byt = (u32)((crow[i]*BK + ckk[i])*2) ^ ((u32)(crow[i]&7)<<4);
      *(s16x8*)((char*)As + buf*16384 + byt) = ra[i];
    }
  };

  const int wv = tid >> 6, lane = tid & 63;
  const int lr = lane & 15, lk = lane >> 4;
  const int wr = (wv >> 1) * 64, wc = (wv & 1) * 64;
  const int cgb = e*16 + hh*8 + (wv & 1)*4;    // col-group base for this wave

  f32x4 acc[4][4];
  #pragma unroll
  for (int i = 0; i < 4; ++i)
    #pragma unroll
    for (int j = 0; j < 4; ++j) acc[i][j] = (f32x4){0.f,0.f,0.f,0.f};

  loadregs(0); writeregs(0);
  int cur = 0;
  const int NK = DIN / BK;   // 8
  for (int ks = 0; ks < NK; ++ks){
    __syncthreads();
    if (ks + 1 < NK) loadregs(ks + 1);
    #pragma unroll
    for (int sub = 0; sub < 2; ++sub){
      int kc = ks*8 + sub*4 + lk;
      s16x8 af[4], bf[4];
      #pragma unroll
      for (int g = 0; g < 4; ++g){
        int arow = wr + g*16 + lr;
        u32 ab = (u32)((arow*BK + sub*32 + lk*8)*2) ^ ((u32)(arow&7)<<4);
        af[g] = *(const s16x8*)((char*)As + cur*16384 + ab);
        bf[g] = *(const s16x8*)(w1f + ((size_t)(cgb + g)*64 + kc)*128 + lr*8);
      }
      #pragma unroll
      for (int i = 0; i < 4; ++i)
        #pragma unroll
        for (int j = 0; j < 4; ++j)
          acc[i][j] = __builtin_amdgcn_mfma_f32_16x16x32_bf16(af[i], bf[j], acc[i][j], 0, 0, 0);
    }
    if (ks + 1 < NK) writeregs(cur ^ 1);
    cur ^= 1;
  }
  __syncthreads();

  u16* outh = (u16*)pool;            // [128][136]
  const int n0 = hh * 128;
  #pragma unroll
  for (int j = 0; j < 4; ++j){
    int col = wc + j*16 + lr;
    float bias = b1[e*HDIM + n0 + col];
    #pragma unroll
    for (int i = 0; i < 4; ++i)
      #pragma unroll
      for (int r = 0; r < 4; ++r){
        int row = wr + i*16 + lk*4 + r;
        float v = acc[i][j][r] + bias;
        outh[row*136 + col] = f2b(v > 0.f ? v : 0.f);
      }
  }
  __syncthreads();
  {
    int r = tid >> 1, half = tid & 1;
    if (c0 + r < cnt){
      u16* dst = h + (size_t)(off + c0 + r) * HDIM + n0 + half*64;
      const u16* src = outh + r*136 + half*64;
      #pragma unroll
      for (int q = 0; q < 8; ++q)
        *(s16x8*)(dst + q*8) = *(const s16x8*)(src + q*8);
    }
  }
}

// ---------------- k_y: bf16-strided combined (+)= w_slot * (h W2e + b2e); B tiled ----------
template<int PASS>
__global__ __launch_bounds__(256, 3) void k_y(
    const u16* __restrict__ h, const u16* __restrict__ w2f, const float* __restrict__ b2,
    const int* __restrict__ offsets, const int* __restrict__ tok_slot,
    const float* __restrict__ w_slot, u16* __restrict__ cmb)
{
  __shared__ __align__(16) char pool[34816];   // As dbuf 2x16K; reused as outh [128][136]
  u16* As = (u16*)pool;
  __shared__ int   toks[BM];
  __shared__ float wts[BM];
  const int e    = blockIdx.z;
  const int q4   = blockIdx.y;                 // DOUT quarter
  const int segb = offsets[2*e + PASS];
  const int segc = offsets[2*e + PASS + 1] - segb;
  const int c0   = blockIdx.x * BM;
  if (c0 >= segc) return;
  const int n0   = q4 * BN;
  const int tid  = threadIdx.x;

  if (tid < BM){
    int r = c0 + tid;
    int s = segb + (r < segc ? r : segc - 1);
    toks[tid] = tok_slot[s];
    wts[tid]  = w_slot[s];
  }
  __syncthreads();

  const u16* Ag = h + (size_t)(segb + c0) * HDIM;

  int crow[4], ckk[4];
  #pragma unroll
  for (int i = 0; i < 4; ++i){
    int c = tid + i*256;
    crow[i] = c >> 3; ckk[i] = (c & 7) * 8;
  }
  s16x8 ra[4];
  auto loadregs = [&](int ks){
    #pragma unroll
    for (int i = 0; i < 4; ++i)
      ra[i] = *(const s16x8*)(Ag + (size_t)crow[i]*HDIM + ks*BK + ckk[i]);
  };
  auto writeregs = [&](int buf){
    #pragma unroll
    for (int i = 0; i < 4; ++i){
      u32 byt = (u32)((crow[i]*BK + ckk[i])*2) ^ ((u32)(crow[i]&7)<<4);
      *(s16x8*)((char*)As + buf*16384 + byt) = ra[i];
    }
  };

  const int wv = tid >> 6, lane = tid & 63;
  const int lr = lane & 15, lk = lane >> 4;
  const int wr = (wv >> 1) * 64, wc = (wv & 1) * 64;
  const int cgb = e*32 + q4*8 + (wv & 1)*4;

  f32x4 acc[4][4];
  #pragma unroll
  for (int i = 0; i < 4; ++i)
    #pragma unroll
    for (int j = 0; j < 4; ++j) acc[i][j] = (f32x4){0.f,0.f,0.f,0.f};

  loadregs(0); writeregs(0);
  int cur = 0;
  const int NK = HDIM / BK;  // 4
  for (int ks = 0; ks < NK; ++ks){
    __syncthreads();
    if (ks + 1 < NK) loadregs(ks + 1);
    #pragma unroll
    for (int sub = 0; sub < 2; ++sub){
      int kc = ks*8 + sub*4 + lk;
      s16x8 af[4], bf[4];
      #pragma unroll
      for (int g = 0; g < 4; ++g){
        int arow = wr + g*16 + lr;
        u32 ab = (u32)((arow*BK + sub*32 + lk*8)*2) ^ ((u32)(arow&7)<<4);
        af[g] = *(const s16x8*)((char*)As + cur*16384 + ab);
        bf[g] = *(const s16x8*)(w2f + ((size_t)(cgb + g)*32 + kc)*128 + lr*8);
      }
      #pragma unroll
      for (int i = 0; i < 4; ++i)
        #pragma unroll
        for (int j = 0; j < 4; ++j)
          acc[i][j] = __builtin_amdgcn_mfma_f32_16x16x32_bf16(af[i], bf[j], acc[i][j], 0, 0, 0);
    }
    if (ks + 1 < NK) writeregs(cur ^ 1);
    cur ^= 1;
  }
  __syncthreads();

  u16* outh = (u16*)pool;            // [128][136] bf16
  #pragma unroll
  for (int j = 0; j < 4; ++j){
    int col = wc + j*16 + lr;
    float bias = b2[e*DOUT + n0 + col];
    #pragma unroll
    for (int i = 0; i < 4; ++i)
      #pragma unroll
      for (int r = 0; r < 4; ++r){
        int row = wr + i*16 + lk*4 + r;
        outh[row*136 + col] = f2b(wts[row] * (acc[i][j][r] + bias));
      }
  }
  __syncthreads();
  {
    int r = tid >> 1, half = tid & 1;
    if (c0 + r < segc){
      u16* dst = cmb + (size_t)toks[r] * 1024 + n0 + half*64;
      const u16* src = outh + r*136 + half*64;
      #pragma unroll
      for (int q = 0; q < 8; ++q){
        s16x8 s = *(const s16x8*)(src + q*8);
        if (PASS == 1){
          s16x8 old = *(const s16x8*)(dst + q*8);
          #pragma unroll
          for (int m = 0; m < 8; ++m)
            s[m] = (short)f2b(b2f((u16)old[m]) + b2f((u16)s[m]));
        }
        *(s16x8*)(dst + q*8) = s;
      }
    }
  }
}

// ---------------- k_cls: DISJOINT: reads strided cmb [32,64M), writes cls [0,32M) ----------
__global__ __launch_bounds__(512, 4) void k_cls(
    const u16* __restrict__ cmb, const float* __restrict__ W,
    const float* __restrict__ bias, float* __restrict__ out)
{
  __shared__ __align__(16) char Bs[2][10240];   // 128 cols x 80B
  const int tid = threadIdx.x;
  const int r0  = blockIdx.x * 256;
  const int c0  = blockIdx.y * 128;

  const int bc4 = tid >> 4;
  const int bkp = tid & 15;
  u32 bpk[4];
  auto loadB = [&](int ks){
    const float* p0 = W + (size_t)(ks*32 + 2*bkp) * DOUT + c0 + bc4*4;
    f32x4 v0 = *(const f32x4*)p0;
    f32x4 v1 = *(const f32x4*)(p0 + DOUT);
    #pragma unroll
    for (int m = 0; m < 4; ++m) bpk[m] = pk2(v0[m], v1[m]);
  };
  auto writeB = [&](int buf){
    #pragma unroll
    for (int m = 0; m < 4; ++m)
      *(u32*)(Bs[buf] + (bc4*4 + m)*80 + bkp*4) = bpk[m];
  };

  const int wv = tid >> 6, lane = tid & 63;
  const int lr = lane & 15, lk = lane >> 4;
  const int rg = wv >> 1, cg = wv & 1;
  const u16* Arow = cmb + (size_t)(r0 + rg*64) * 1024;

  f32x4 acc[4][4];
  #pragma unroll
  for (int i = 0; i < 4; ++i)
    #pragma unroll
    for (int j = 0; j < 4; ++j) acc[i][j] = (f32x4){0.f,0.f,0.f,0.f};

  s16x8 af[4], afn[4];
  auto loadA = [&](s16x8* a, int ks){
    #pragma unroll
    for (int g = 0; g < 4; ++g)
      a[g] = *(const s16x8*)(Arow + (size_t)(g*16 + lr)*1024 + ks*32 + lk*8);
  };

  loadB(0); writeB(0); loadA(af, 0);
  int cur = 0;
  for (int ks = 0; ks < 16; ++ks){
    __syncthreads();
    if (ks + 1 < 16){ loadB(ks + 1); loadA(afn, ks + 1); }
    s16x8 bf[4];
    #pragma unroll
    for (int j = 0; j < 4; ++j)
      bf[j] = *(const s16x8*)(Bs[cur] + (cg*64 + j*16 + lr)*80 + lk*16);
    #pragma unroll
    for (int i = 0; i < 4; ++i)
      #pragma unroll
      for (int j = 0; j < 4; ++j)
        acc[i][j] = __builtin_amdgcn_mfma_f32_16x16x32_bf16(af[i], bf[j], acc[i][j], 0, 0, 0);
    if (ks + 1 < 16) writeB(cur ^ 1);
    #pragma unroll
    for (int g = 0; g < 4; ++g) af[g] = afn[g];
    cur ^= 1;
  }

  #pragma unroll
  for (int j = 0; j < 4; ++j){
    int col = c0 + cg*64 + j*16 + lr;
    float bv = bias[col];
    #pragma unroll
    for (int i = 0; i < 4; ++i)
      #pragma unroll
      for (int r = 0; r < 4; ++r){
        int row = r0 + rg*64 + i*16 + lk*4 + r;
        out[(size_t)row * DOUT + col] = acc[i][j][r] + bv;
      }
  }
}

// ---------------- k_vip (fallback): vec in place, 64-row blocks ----------------
__global__ __launch_bounds__(512, 2) void k_vip(
    const float* __restrict__ W, const float* __restrict__ bias,
    u16* __restrict__ cmbio)
{
  __shared__ __align__(16) char Bs[2][40960];
  const int tid = threadIdx.x;
  const int r0  = blockIdx.x * 64;

  int bc4[4], bkp[4];
  #pragma unroll
  for (int u = 0; u < 4; ++u){
    int idx = tid + u*512;
    bc4[u] = idx >> 4;
    bkp[u] = idx & 15;
  }
  u32 bpk[4][4];
  auto loadB = [&](int ks){
    #pragma unroll
    for (int u = 0; u < 4; ++u){
      const float* p0 = W + (size_t)(ks*32 + 2*bkp[u]) * DOUT + bc4[u]*4;
      f32x4 v0 = *(const f32x4*)p0;
      f32x4 v1 = *(const f32x4*)(p0 + DOUT);
      #pragma unroll
      for (int m = 0; m < 4; ++m) bpk[u][m] = pk2(v0[m], v1[m]);
    }
  };
  auto writeB = [&](int buf){
    #pragma unroll
    for (int u = 0; u < 4; ++u)
      #pragma unroll
      for (int m = 0; m < 4; ++m)
        *(u32*)(Bs[buf] + (bc4[u]*4 + m)*80 + bkp[u]*4) = bpk[u][m];
  };

  const int wv = tid >> 6, lane = tid & 63;
  const int lr = lane & 15, lk = lane >> 4;
  const int wc = wv * 64;
  const u16* Arow = cmbio + (size_t)r0 * 1024;

  f32x4 acc[4][4];
  #pragma unroll
  for (int i = 0; i < 4; ++i)
    #pragma unroll
    for (int j = 0; j < 4; ++j) acc[i][j] = (f32x4){0.f,0.f,0.f,0.f};

  s16x8 af[4], afn[4];
  auto loadA = [&](s16x8* a, int ks){
    #pragma unroll
    for (int g = 0; g < 4; ++g)
      a[g] = *(const s16x8*)(Arow + (size_t)(g*16 + lr)*1024 + ks*32 + lk*8);
  };

  loadB(0); writeB(0); loadA(af, 0);
  int cur = 0;
  for (int ks = 0; ks < 16; ++ks){
    __syncthreads();
    if (ks + 1 < 16){ loadB(ks + 1); loadA(afn, ks + 1); }
    s16x8 bf[4];
    #pragma unroll
    for (int g = 0; g < 4; ++g)
      bf[g] = *(const s16x8*)(Bs[cur] + (wc + g*16 + lr)*80 + lk*16);
    #pragma unroll
    for (int i = 0; i < 4; ++i)
      #pragma unroll
      for (int j = 0; j < 4; ++j)
        acc[i][j] = __builtin_amdgcn_mfma_f32_16x16x32_bf16(af[i], bf[j], acc[i][j], 0, 0, 0);
    if (ks + 1 < 16) writeB(cur ^ 1);
    #pragma unroll
    for (int g = 0; g < 4; ++g) af[g] = afn[g];
    cur ^= 1;
  }
  __syncthreads();

  float* out = (float*)cmbio;
  #pragma unroll
  for (int j = 0; j < 4; ++j){
    int col = wc + j*16 + lr;
    float bv = bias[col];
    #pragma unroll
    for (int i = 0; i < 4; ++i)
      #pragma unroll
      for (int r = 0; r < 4; ++r){
        int row = r0 + i*16 + lk*4 + r;
        out[(size_t)row * DOUT + col] = acc[i][j][r] + bv;
      }
  }
}

// ---------------- k_vipw (ws path): vec in place, tiled-B from d_ws, 2-deep pipe ----------
__global__ __launch_bounds__(256, 2) void k_vipw(
    const u16* __restrict__ wTt, const float* __restrict__ bias,
    u16* __restrict__ cmbio)
{
  const int tid = threadIdx.x;
  const int r0  = blockIdx.x * 32;
  const int wv = tid >> 6, lane = tid & 63;
  const int lr = lane & 15, lk = lane >> 4;
  const int wc = wv * 128;
  const int cg0 = wv * 8;
  const u16* Arow = cmbio + (size_t)r0 * 1024;

  f32x4 acc[2][8];
  #pragma unroll
  for (int i = 0; i < 2; ++i)
    #pragma unroll
    for (int j = 0; j < 8; ++j) acc[i][j] = (f32x4){0.f,0.f,0.f,0.f};

  s16x8 a0[2], b0[8], a1[2], b1[8];
  auto loadA = [&](s16x8* a, int ks){
    #pragma unroll
    for (int g = 0; g < 2; ++g)
      a[g] = *(const s16x8*)(Arow + (size_t)(g*16 + lr)*1024 + ks*32 + lk*8);
  };
  auto loadB = [&](s16x8* b, int ks){
    #pragma unroll
    for (int j = 0; j < 8; ++j){
      int chunk = (cg0 + j)*64 + ks*4 + lk;
      b[j] = *(const s16x8*)(wTt + (size_t)chunk*128 + lr*8);
    }
  };
  auto step = [&](const s16x8* a, const s16x8* b){
    #pragma unroll
    for (int j = 0; j < 8; ++j)
      #pragma unroll
      for (int i = 0; i < 2; ++i)
        acc[i][j] = __builtin_amdgcn_mfma_f32_16x16x32_bf16(a[i], b[j], acc[i][j], 0, 0, 0);
  };

  loadA(a0, 0); loadB(b0, 0);
  #pragma unroll
  for (int ks = 0; ks < 16; ks += 2){
    if (ks + 1 < 16){ loadA(a1, ks + 1); loadB(b1, ks + 1); }
    step(a0, b0);
    if (ks + 2 < 16){ loadA(a0, ks + 2); loadB(b0, ks + 2); }
    step(a1, b1);
  }
  __syncthreads();

  float* out = (float*)cmbio;
  #pragma unroll
  for (int j = 0; j < 8; ++j){
    int col = wc + j*16 + lr;
    float bv = bias[col];
    #pragma unroll
    for (int i = 0; i < 2; ++i)
      #pragma unroll
      for (int r = 0; r < 4; ++r){
        int row = r0 + i*16 + lk*4 + r;
        out[(size_t)row * DOUT + col] = acc[i][j][r] + bv;
      }
  }
}

extern "C" void kernel_launch(void* const* d_in, const int* in_sizes, int n_in,
                              void* d_out, int out_size, void* d_ws, size_t ws_size,
                              hipStream_t stream)
{
  const float* x    = (const float*)d_in[0];
  const float* gw   = (const float*)d_in[1];
  const float* gb   = (const float*)d_in[2];
  const float* w1   = (const float*)d_in[3];
  const float* b1   = (const float*)d_in[4];
  const float* w2   = (const float*)d_in[5];
  const float* b2   = (const float*)d_in[6];
  const float* clsw = (const float*)d_in[7];
  const float* clsb = (const float*)d_in[8];
  const float* vecw = (const float*)d_in[9];
  const float* vecb = (const float*)d_in[10];

  char* base = (char*)d_out;
  float* cls_out  = (float*)base;                               // [0,32Mi)
  u16*   cmb      = (u16*)(base + ((size_t)32<<20));            // strided in vec half
  u16*   h        = (u16*)base;                                 // [0,16Mi)
  char*  mb       = base + ((size_t)16<<20) + (128<<10);
  int*   tok_slot = (int*)  mb;
  float* w_slot   = (float*)(mb + 131072);
  int*   tke      = (int*)  (mb + 262144);
  float* tkw      = (float*)(mb + 393216);
  int*   counts   = (int*)  (mb + 524288);
  int*   offsets  = (int*)  (mb + 524544);
  int*   cursors  = (int*)  (mb + 524800);
  u16*   w1f      = (u16*)(base + ((size_t)18<<20));            // tiled bf16, 2.62MB
  u16*   w2f      = (u16*)(base + ((size_t)21<<20));            // tiled bf16, 2.62MB

  const bool usews = (ws_size >= (size_t)(1<<20));
  u16* vecwTt = (u16*)d_ws;            // fragment-tiled vec weight, 512KB

  k_zero<<<dim3(1), dim3(64), 0, stream>>>(counts);
  k_gate<<<dim3(NTOK/16), dim3(256), 0, stream>>>(x, gw, gb, tke, tkw, counts);
  k_scan<<<dim3(1), dim3(64), 0, stream>>>(counts, offsets, cursors);
  k_scatter<<<dim3(NTOK/256), dim3(256), 0, stream>>>(tke, tkw, offsets, cursors,
                                                      tok_slot, w_slot);
  // tiled weights: w1 (K=DIN=512 -> KC8=64, C=HDIM=256 -> C16=16), per-expert 16384 threads
  k_wtf<<<dim3(64, 1, NEXP), dim3(256), 0, stream>>>(w1, w1f, 64, 16);
  // w2 (K=HDIM=256 -> KC8=32, C=DOUT=512 -> C16=32)
  k_wtf<<<dim3(64, 1, NEXP), dim3(256), 0, stream>>>(w2, w2f, 32, 32);
  if (usews)
    k_wtf<<<dim3(128, 1, 1), dim3(256), 0, stream>>>(vecw, vecwTt, 64, 32);
  k_h<<<dim3(256, 2, NEXP), dim3(256), 0, stream>>>(x, w1f, b1, offsets, tok_slot, h);
  k_y<0><<<dim3(128, 4, NEXP), dim3(256), 0, stream>>>(h, w2f, b2, offsets, tok_slot, w_slot, cmb);
  k_y<1><<<dim3(128, 4, NEXP), dim3(256), 0, stream>>>(h, w2f, b2, offsets, tok_slot, w_slot, cmb);
  k_cls<<<dim3(NTOK/256, DOUT/128), dim3(512), 0, stream>>>(cmb, clsw, clsb, cls_out);
  if (usews)
    k_vipw<<<dim3(NTOK/32), dim3(256), 0, stream>>>(vecwTt, vecb, cmb);
  else
    k_vip<<<dim3(NTOK/64), dim3(512), 0, stream>>>(vecw, vecb, cmb);
}